// Round 4
// baseline (294.680 us; speedup 1.0000x reference)
//
#include <hip/hip_runtime.h>
#include <hip/hip_bf16.h>
#include <stdint.h>

#define BATCH 16384
#define D 1024
#define NCLS 1000
#define NPROTO 5000
#define NPROTO_PAD 5120
#define BM 256
#define BN 256
#define BK 64
#define NIT (D / (2 * BK))   // 8 iterations, 2 K-tiles each

typedef float f32x4 __attribute__((ext_vector_type(4)));
typedef __bf16 bf16x8 __attribute__((ext_vector_type(8)));

__device__ __forceinline__ unsigned short f2bf(float x) {
    unsigned u = __float_as_uint(x);
    u += 0x7FFFu + ((u >> 16) & 1u);   // RNE
    return (unsigned short)(u >> 16);
}
__device__ __forceinline__ unsigned enc_f32(float f) {
    unsigned u = __float_as_uint(f);
    return (u & 0x80000000u) ? ~u : (u | 0x80000000u);
}
__device__ __forceinline__ float dec_f32(unsigned e) {
    return __uint_as_float((e & 0x80000000u) ? (e ^ 0x80000000u) : ~e);
}

// ---------- normalize rows of z and P to bf16, init atomic cells ----------
__global__ __launch_bounds__(256) void k_prep(
        const float* __restrict__ z, const float* __restrict__ P,
        unsigned short* __restrict__ zb, unsigned short* __restrict__ pb,
        unsigned* __restrict__ posU, unsigned* __restrict__ negU) {
    const int b = blockIdx.x;
    const int t = threadIdx.x;
    if (b < BATCH && t == 0) {
        posU[b] = enc_f32(-INFINITY);
        negU[b] = enc_f32(-INFINITY);
    }
    const float* src = nullptr;
    unsigned short* dst;
    if (b < BATCH) {
        src = z + (size_t)b * D;
        dst = zb + (size_t)b * D;
    } else {
        const int r = b - BATCH;
        dst = pb + (size_t)r * D;
        if (r < NPROTO) src = P + (size_t)r * D;
    }
    if (src == nullptr) {
        ushort4 zr = make_ushort4(0, 0, 0, 0);
        ((ushort4*)dst)[t] = zr;
        return;
    }
    float4 v = ((const float4*)src)[t];
    float ss = v.x * v.x + v.y * v.y + v.z * v.z + v.w * v.w;
    #pragma unroll
    for (int off = 32; off >= 1; off >>= 1) ss += __shfl_xor(ss, off);
    __shared__ float red[4];
    const int wave = t >> 6;
    if ((t & 63) == 0) red[wave] = ss;
    __syncthreads();
    const float s = red[0] + red[1] + red[2] + red[3];
    const float inv = 1.0f / fmaxf(sqrtf(s), 1e-12f);
    ushort4 o;
    o.x = f2bf(v.x * inv); o.y = f2bf(v.y * inv);
    o.z = f2bf(v.z * inv); o.w = f2bf(v.w * inv);
    ((ushort4*)dst)[t] = o;
}

// async global->LDS, 16B per lane, dest = wave-uniform base + lane*16
#define GLL(gp, lp) __builtin_amdgcn_global_load_lds( \
    (__attribute__((address_space(1))) const unsigned int*)(const void*)(gp), \
    (__attribute__((address_space(3))) unsigned int*)(void*)(lp), 16, 0, 0)

#define MM(A, B, C) __builtin_amdgcn_mfma_f32_16x16x32_bf16(A, B, C, 0, 0, 0)

// ---------- 256x256 bf16 MFMA GEMM, 8-phase, race-free gating ----------
// Gating invariant: every slab consumed at phase p was staged 3-4 phases
// earlier and covered by a (vmcnt(4) by ALL waves -> s_barrier) pair at
// phase p-1 end. vmcnt(4) at phase-end completes the pair staged 2 phases
// back (steady state: start 4 outstanding, +2 stage, wait -> 4).
__global__ __launch_bounds__(512, 2) void k_gemm(
        const unsigned short* __restrict__ zb,
        const unsigned short* __restrict__ pb,
        const int* __restrict__ y,
        unsigned* __restrict__ posU, unsigned* __restrict__ negU) {
    // fragment-packed LDS: [kbuf][A=0/B=1][frag 0..15][ks 0..1][lane][8]
    __shared__ __align__(16) unsigned short L[2][2][16][2][64][8];  // 128 KiB

    const int t = threadIdx.x;
    const int w = t >> 6;
    const int lane = t & 63;
    const int lm = lane & 15, lk = lane >> 4;
    const int wm = w >> 2, wn = w & 3;       // 2(M) x 4(N) wave grid

    const int rowbase = blockIdx.y * BM;
    const int colbase = blockIdx.x * BN;

    // stage sources: wave w supplies frags w (rows w*16+lm) and w+8 (+128)
    const unsigned short* pA0 = zb + (size_t)(rowbase + w * 16 + lm) * D + lk * 8;
    const unsigned short* pA1 = pA0 + (size_t)128 * D;
    const unsigned short* pB0 = pb + (size_t)(colbase + w * 16 + lm) * D + lk * 8;
    const unsigned short* pB1 = pB0 + (size_t)128 * D;

#define STG_A(T, KS) do {                                               \
    GLL(pA0 + (T) * 64 + (KS) * 32, &L[(T) & 1][0][w][KS][0][0]);       \
    GLL(pA1 + (T) * 64 + (KS) * 32, &L[(T) & 1][0][w + 8][KS][0][0]);   \
} while (0)
#define STG_B(T, KS) do {                                               \
    GLL(pB0 + (T) * 64 + (KS) * 32, &L[(T) & 1][1][w][KS][0][0]);       \
    GLL(pB1 + (T) * 64 + (KS) * 32, &L[(T) & 1][1][w + 8][KS][0][0]);   \
} while (0)

#define LDA(BUF, FR, KS) (*(const bf16x8*)&L[BUF][0][FR][KS][lane][0])
#define LDB(BUF, FR, KS) (*(const bf16x8*)&L[BUF][1][FR][KS][lane][0])

#define WV4 asm volatile("s_waitcnt vmcnt(4)" ::: "memory")
#define WV2 asm volatile("s_waitcnt vmcnt(2)" ::: "memory")
#define WV0 asm volatile("s_waitcnt vmcnt(0)" ::: "memory")
#define NOV ((void)0)
#define NOS ((void)0)

    f32x4 acc[8][4];
    #pragma unroll
    for (int i = 0; i < 8; ++i)
        #pragma unroll
        for (int j = 0; j < 4; ++j) {
            f32x4 z4 = {0.0f, 0.0f, 0.0f, 0.0f};
            acc[i][j] = z4;
        }

    bf16x8 b0_, b1_, b2_, b3_;

// phase: reads -> stage -> mid-barrier -> lgkm0 -> 16 MFMA -> vmcnt -> barrier
#define PH(CBUF, MH, KS, RB, STG, WAIT) do {                             \
    const bf16x8 a0_ = LDA(CBUF, 8 * wm + 4 * (MH) + 0, KS);             \
    const bf16x8 a1_ = LDA(CBUF, 8 * wm + 4 * (MH) + 1, KS);             \
    const bf16x8 a2_ = LDA(CBUF, 8 * wm + 4 * (MH) + 2, KS);             \
    const bf16x8 a3_ = LDA(CBUF, 8 * wm + 4 * (MH) + 3, KS);             \
    if (RB) {                                                            \
        b0_ = LDB(CBUF, 4 * wn + 0, KS);                                 \
        b1_ = LDB(CBUF, 4 * wn + 1, KS);                                 \
        b2_ = LDB(CBUF, 4 * wn + 2, KS);                                 \
        b3_ = LDB(CBUF, 4 * wn + 3, KS);                                 \
    }                                                                    \
    STG;                                                                 \
    asm volatile("s_barrier" ::: "memory");                              \
    asm volatile("s_waitcnt lgkmcnt(0)" ::: "memory");                   \
    __builtin_amdgcn_s_setprio(1);                                       \
    acc[4 * (MH) + 0][0] = MM(a0_, b0_, acc[4 * (MH) + 0][0]);           \
    acc[4 * (MH) + 0][1] = MM(a0_, b1_, acc[4 * (MH) + 0][1]);           \
    acc[4 * (MH) + 0][2] = MM(a0_, b2_, acc[4 * (MH) + 0][2]);           \
    acc[4 * (MH) + 0][3] = MM(a0_, b3_, acc[4 * (MH) + 0][3]);           \
    acc[4 * (MH) + 1][0] = MM(a1_, b0_, acc[4 * (MH) + 1][0]);           \
    acc[4 * (MH) + 1][1] = MM(a1_, b1_, acc[4 * (MH) + 1][1]);           \
    acc[4 * (MH) + 1][2] = MM(a1_, b2_, acc[4 * (MH) + 1][2]);           \
    acc[4 * (MH) + 1][3] = MM(a1_, b3_, acc[4 * (MH) + 1][3]);           \
    acc[4 * (MH) + 2][0] = MM(a2_, b0_, acc[4 * (MH) + 2][0]);           \
    acc[4 * (MH) + 2][1] = MM(a2_, b1_, acc[4 * (MH) + 2][1]);           \
    acc[4 * (MH) + 2][2] = MM(a2_, b2_, acc[4 * (MH) + 2][2]);           \
    acc[4 * (MH) + 2][3] = MM(a2_, b3_, acc[4 * (MH) + 2][3]);           \
    acc[4 * (MH) + 3][0] = MM(a3_, b0_, acc[4 * (MH) + 3][0]);           \
    acc[4 * (MH) + 3][1] = MM(a3_, b1_, acc[4 * (MH) + 3][1]);           \
    acc[4 * (MH) + 3][2] = MM(a3_, b2_, acc[4 * (MH) + 3][2]);           \
    acc[4 * (MH) + 3][3] = MM(a3_, b3_, acc[4 * (MH) + 3][3]);           \
    __builtin_amdgcn_s_setprio(0);                                       \
    WAIT;                                                                \
    asm volatile("s_barrier" ::: "memory");                              \
} while (0)

    // prologue: stage tile 0 fully, drain, barrier
    STG_A(0, 0); STG_B(0, 0); STG_A(0, 1); STG_B(0, 1);
    WV0;
    asm volatile("s_barrier" ::: "memory");

    // iter i: compute tile 2i (buf0, PH1-4) + tile 2i+1 (buf1, PH5-8);
    // stage tile 2i+1 -> buf1 during PH1-4, tile 2i+2 -> buf0 during PH5-8.
    #pragma unroll 1
    for (int i = 0; i < NIT - 1; ++i) {
        const int o1 = 2 * i + 1, e2 = 2 * i + 2;
        PH(0, 0, 0, 1, STG_A(o1, 0), WV4);
        PH(0, 1, 0, 0, STG_B(o1, 0), WV4);
        PH(0, 0, 1, 1, STG_A(o1, 1), WV4);
        PH(0, 1, 1, 0, STG_B(o1, 1), WV4);
        PH(1, 0, 0, 1, STG_A(e2, 0), WV4);
        PH(1, 1, 0, 0, STG_B(e2, 0), WV4);
        PH(1, 0, 1, 1, STG_A(e2, 1), WV4);
        PH(1, 1, 1, 0, STG_B(e2, 1), WV4);
    }
    // tail iter 7: tiles 14,15; stage only tile 15; drain waits 4,4,4,4,2,0
    PH(0, 0, 0, 1, STG_A(15, 0), WV4);
    PH(0, 1, 0, 0, STG_B(15, 0), WV4);
    PH(0, 0, 1, 1, STG_A(15, 1), WV4);
    PH(0, 1, 1, 0, STG_B(15, 1), WV4);
    PH(1, 0, 0, 1, NOS, WV2);
    PH(1, 1, 0, 0, NOS, WV0);
    PH(1, 0, 1, 1, NOS, NOV);
    PH(1, 1, 1, 0, NOS, NOV);

    // fused epilogue: masked pos/neg max per output row
    // C/D layout: col = lane&15 (proto), row = (lane>>4)*4 + reg (batch)
    const int col00 = colbase + wn * 64 + lm;
    #pragma unroll
    for (int mi = 0; mi < 8; ++mi) {
        #pragma unroll
        for (int r = 0; r < 4; ++r) {
            const int row_g = rowbase + wm * 128 + mi * 16 + lk * 4 + r;
            const int yv = y[row_g];
            float pm = -INFINITY, nm = -INFINITY;
            #pragma unroll
            for (int ni = 0; ni < 4; ++ni) {
                const int col_g = col00 + ni * 16;
                const float v = acc[mi][ni][r];
                const bool same = (col_g / 5) == yv;
                if (same) pm = fmaxf(pm, v);
                else if (col_g < NPROTO) nm = fmaxf(nm, v);
            }
            #pragma unroll
            for (int off = 1; off < 16; off <<= 1) {
                pm = fmaxf(pm, __shfl_xor(pm, off));
                nm = fmaxf(nm, __shfl_xor(nm, off));
            }
            if (lm == 0) {
                if (pm > -INFINITY) atomicMax(&posU[row_g], enc_f32(pm));
                if (nm > -INFINITY) atomicMax(&negU[row_g], enc_f32(nm));
            }
        }
    }
#undef PH
#undef STG_A
#undef STG_B
}

// ---------- decode to output ----------
__global__ __launch_bounds__(256) void k_finish(
        const unsigned* __restrict__ posU, const unsigned* __restrict__ negU,
        float* __restrict__ out) {
    const int i = blockIdx.x * 256 + threadIdx.x;
    if (i < BATCH) {
        out[i] = dec_f32(posU[i]);
        out[BATCH + i] = dec_f32(negU[i]);
    }
}

extern "C" void kernel_launch(void* const* d_in, const int* in_sizes, int n_in,
                              void* d_out, int out_size, void* d_ws, size_t ws_size,
                              hipStream_t stream) {
    const float* z = (const float*)d_in[0];
    const int*   y = (const int*)d_in[1];
    const float* P = (const float*)d_in[2];

    unsigned short* zb = (unsigned short*)d_ws;
    unsigned short* pb = zb + (size_t)BATCH * D;
    unsigned* posU = (unsigned*)(pb + (size_t)NPROTO_PAD * D);
    unsigned* negU = posU + BATCH;
    float* out = (float*)d_out;

    k_prep<<<BATCH + NPROTO_PAD, 256, 0, stream>>>(z, P, zb, pb, posU, negU);
    dim3 grid(NPROTO_PAD / BN, BATCH / BM);
    k_gemm<<<grid, 512, 0, stream>>>(zb, pb, y, posU, negU);
    k_finish<<<BATCH / 256, 256, 0, stream>>>(posU, negU, out);
}

// Round 5
// 289.314 us; speedup vs baseline: 1.0186x; 1.0186x over previous
//
#include <hip/hip_runtime.h>
#include <hip/hip_bf16.h>
#include <stdint.h>

#define BATCH 16384
#define D 1024
#define NCLS 1000
#define NPROTO 5000
#define NPROTO_PAD 5120
#define BM 256
#define BN 256
#define BK 64
#define NIT (D / (2 * BK))   // 8 iterations, 2 K-tiles each
#define NBLK ((NPROTO_PAD / BN) * (BATCH / BM))   // 20 * 64 = 1280

typedef float f32x4 __attribute__((ext_vector_type(4)));
typedef __bf16 bf16x8 __attribute__((ext_vector_type(8)));

__device__ __forceinline__ unsigned short f2bf(float x) {
    unsigned u = __float_as_uint(x);
    u += 0x7FFFu + ((u >> 16) & 1u);   // RNE
    return (unsigned short)(u >> 16);
}
__device__ __forceinline__ unsigned enc_f32(float f) {
    unsigned u = __float_as_uint(f);
    return (u & 0x80000000u) ? ~u : (u | 0x80000000u);
}
__device__ __forceinline__ float dec_f32(unsigned e) {
    return __uint_as_float((e & 0x80000000u) ? (e ^ 0x80000000u) : ~e);
}

// ---------- normalize rows of z and P to bf16, init atomic cells ----------
__global__ __launch_bounds__(256) void k_prep(
        const float* __restrict__ z, const float* __restrict__ P,
        unsigned short* __restrict__ zb, unsigned short* __restrict__ pb,
        unsigned* __restrict__ posU, unsigned* __restrict__ negU) {
    const int b = blockIdx.x;
    const int t = threadIdx.x;
    if (b < BATCH && t == 0) {
        posU[b] = enc_f32(-INFINITY);
        negU[b] = enc_f32(-INFINITY);
    }
    const float* src = nullptr;
    unsigned short* dst;
    if (b < BATCH) {
        src = z + (size_t)b * D;
        dst = zb + (size_t)b * D;
    } else {
        const int r = b - BATCH;
        dst = pb + (size_t)r * D;
        if (r < NPROTO) src = P + (size_t)r * D;
    }
    if (src == nullptr) {
        ushort4 zr = make_ushort4(0, 0, 0, 0);
        ((ushort4*)dst)[t] = zr;
        return;
    }
    float4 v = ((const float4*)src)[t];
    float ss = v.x * v.x + v.y * v.y + v.z * v.z + v.w * v.w;
    #pragma unroll
    for (int off = 32; off >= 1; off >>= 1) ss += __shfl_xor(ss, off);
    __shared__ float red[4];
    const int wave = t >> 6;
    if ((t & 63) == 0) red[wave] = ss;
    __syncthreads();
    const float s = red[0] + red[1] + red[2] + red[3];
    const float inv = 1.0f / fmaxf(sqrtf(s), 1e-12f);
    ushort4 o;
    o.x = f2bf(v.x * inv); o.y = f2bf(v.y * inv);
    o.z = f2bf(v.z * inv); o.w = f2bf(v.w * inv);
    ((ushort4*)dst)[t] = o;
}

// async global->LDS, 16B per lane, dest = wave-uniform base + lane*16
#define GLL(gp, lp) __builtin_amdgcn_global_load_lds( \
    (__attribute__((address_space(1))) const unsigned int*)(const void*)(gp), \
    (__attribute__((address_space(3))) unsigned int*)(void*)(lp), 16, 0, 0)

#define MM(A, B, C) __builtin_amdgcn_mfma_f32_16x16x32_bf16(A, B, C, 0, 0, 0)

// ---------- 256x256 bf16 MFMA GEMM, 8-phase, XCD-locality swizzle ----------
// T1 swizzle: xcd = bid&7 owns row-panels [xcd*8, xcd*8+8); within an XCD,
// 8 consecutive blocks share one B-panel (L2-hot), the 8 A-panels (4 MB)
// stay L2-resident for the kernel's lifetime.
__global__ __launch_bounds__(512, 2) void k_gemm(
        const unsigned short* __restrict__ zb,
        const unsigned short* __restrict__ pb,
        const int* __restrict__ y,
        unsigned* __restrict__ posU, unsigned* __restrict__ negU) {
    // fragment-packed LDS: [kbuf][A=0/B=1][frag 0..15][ks 0..1][lane][8]
    __shared__ __align__(16) unsigned short L[2][2][16][2][64][8];  // 128 KiB

    const int t = threadIdx.x;
    const int w = t >> 6;
    const int lane = t & 63;
    const int lm = lane & 15, lk = lane >> 4;
    const int wm = w >> 2, wn = w & 3;       // 2(M) x 4(N) wave grid

    // XCD-aware decode: bid&7 = xcd, 8-block runs share a B col-panel
    const int bid = blockIdx.x;
    const int yy = (bid & 7) * 8 + ((bid >> 3) & 7);   // row-tile 0..63
    const int cc = bid >> 6;                           // col-tile 0..19
    const int rowbase = yy * BM;
    const int colbase = cc * BN;

    // stage sources: wave w supplies frags w (rows w*16+lm) and w+8 (+128)
    const unsigned short* pA0 = zb + (size_t)(rowbase + w * 16 + lm) * D + lk * 8;
    const unsigned short* pA1 = pA0 + (size_t)128 * D;
    const unsigned short* pB0 = pb + (size_t)(colbase + w * 16 + lm) * D + lk * 8;
    const unsigned short* pB1 = pB0 + (size_t)128 * D;

#define STG_A(T, KS) do {                                               \
    GLL(pA0 + (T) * 64 + (KS) * 32, &L[(T) & 1][0][w][KS][0][0]);       \
    GLL(pA1 + (T) * 64 + (KS) * 32, &L[(T) & 1][0][w + 8][KS][0][0]);   \
} while (0)
#define STG_B(T, KS) do {                                               \
    GLL(pB0 + (T) * 64 + (KS) * 32, &L[(T) & 1][1][w][KS][0][0]);       \
    GLL(pB1 + (T) * 64 + (KS) * 32, &L[(T) & 1][1][w + 8][KS][0][0]);   \
} while (0)

#define LDA(BUF, FR, KS) (*(const bf16x8*)&L[BUF][0][FR][KS][lane][0])
#define LDB(BUF, FR, KS) (*(const bf16x8*)&L[BUF][1][FR][KS][lane][0])

#define WV4 asm volatile("s_waitcnt vmcnt(4)" ::: "memory")
#define WV2 asm volatile("s_waitcnt vmcnt(2)" ::: "memory")
#define WV0 asm volatile("s_waitcnt vmcnt(0)" ::: "memory")
#define NOV ((void)0)
#define NOS ((void)0)

    f32x4 acc[8][4];
    #pragma unroll
    for (int i = 0; i < 8; ++i)
        #pragma unroll
        for (int j = 0; j < 4; ++j) {
            f32x4 z4 = {0.0f, 0.0f, 0.0f, 0.0f};
            acc[i][j] = z4;
        }

    bf16x8 b0_, b1_, b2_, b3_;

// phase: reads -> stage -> mid-barrier -> lgkm0 -> 16 MFMA -> vmcnt -> barrier
#define PH(CBUF, MH, KS, RB, STG, WAIT) do {                             \
    const bf16x8 a0_ = LDA(CBUF, 8 * wm + 4 * (MH) + 0, KS);             \
    const bf16x8 a1_ = LDA(CBUF, 8 * wm + 4 * (MH) + 1, KS);             \
    const bf16x8 a2_ = LDA(CBUF, 8 * wm + 4 * (MH) + 2, KS);             \
    const bf16x8 a3_ = LDA(CBUF, 8 * wm + 4 * (MH) + 3, KS);             \
    if (RB) {                                                            \
        b0_ = LDB(CBUF, 4 * wn + 0, KS);                                 \
        b1_ = LDB(CBUF, 4 * wn + 1, KS);                                 \
        b2_ = LDB(CBUF, 4 * wn + 2, KS);                                 \
        b3_ = LDB(CBUF, 4 * wn + 3, KS);                                 \
    }                                                                    \
    STG;                                                                 \
    asm volatile("s_barrier" ::: "memory");                              \
    asm volatile("s_waitcnt lgkmcnt(0)" ::: "memory");                   \
    __builtin_amdgcn_s_setprio(1);                                       \
    acc[4 * (MH) + 0][0] = MM(a0_, b0_, acc[4 * (MH) + 0][0]);           \
    acc[4 * (MH) + 0][1] = MM(a0_, b1_, acc[4 * (MH) + 0][1]);           \
    acc[4 * (MH) + 0][2] = MM(a0_, b2_, acc[4 * (MH) + 0][2]);           \
    acc[4 * (MH) + 0][3] = MM(a0_, b3_, acc[4 * (MH) + 0][3]);           \
    acc[4 * (MH) + 1][0] = MM(a1_, b0_, acc[4 * (MH) + 1][0]);           \
    acc[4 * (MH) + 1][1] = MM(a1_, b1_, acc[4 * (MH) + 1][1]);           \
    acc[4 * (MH) + 1][2] = MM(a1_, b2_, acc[4 * (MH) + 1][2]);           \
    acc[4 * (MH) + 1][3] = MM(a1_, b3_, acc[4 * (MH) + 1][3]);           \
    acc[4 * (MH) + 2][0] = MM(a2_, b0_, acc[4 * (MH) + 2][0]);           \
    acc[4 * (MH) + 2][1] = MM(a2_, b1_, acc[4 * (MH) + 2][1]);           \
    acc[4 * (MH) + 2][2] = MM(a2_, b2_, acc[4 * (MH) + 2][2]);           \
    acc[4 * (MH) + 2][3] = MM(a2_, b3_, acc[4 * (MH) + 2][3]);           \
    acc[4 * (MH) + 3][0] = MM(a3_, b0_, acc[4 * (MH) + 3][0]);           \
    acc[4 * (MH) + 3][1] = MM(a3_, b1_, acc[4 * (MH) + 3][1]);           \
    acc[4 * (MH) + 3][2] = MM(a3_, b2_, acc[4 * (MH) + 3][2]);           \
    acc[4 * (MH) + 3][3] = MM(a3_, b3_, acc[4 * (MH) + 3][3]);           \
    __builtin_amdgcn_s_setprio(0);                                       \
    WAIT;                                                                \
    asm volatile("s_barrier" ::: "memory");                              \
} while (0)

    // prologue: stage tile 0 fully, drain, barrier
    STG_A(0, 0); STG_B(0, 0); STG_A(0, 1); STG_B(0, 1);
    WV0;
    asm volatile("s_barrier" ::: "memory");

    // iter i: compute tile 2i (buf0, PH1-4) + tile 2i+1 (buf1, PH5-8);
    // stage tile 2i+1 -> buf1 during PH1-4, tile 2i+2 -> buf0 during PH5-8.
    #pragma unroll 1
    for (int i = 0; i < NIT - 1; ++i) {
        const int o1 = 2 * i + 1, e2 = 2 * i + 2;
        PH(0, 0, 0, 1, STG_A(o1, 0), WV4);
        PH(0, 1, 0, 0, STG_B(o1, 0), WV4);
        PH(0, 0, 1, 1, STG_A(o1, 1), WV4);
        PH(0, 1, 1, 0, STG_B(o1, 1), WV4);
        PH(1, 0, 0, 1, STG_A(e2, 0), WV4);
        PH(1, 1, 0, 0, STG_B(e2, 0), WV4);
        PH(1, 0, 1, 1, STG_A(e2, 1), WV4);
        PH(1, 1, 1, 0, STG_B(e2, 1), WV4);
    }
    // tail iter 7: tiles 14,15; stage only tile 15; drain waits 4,4,4,4,2,0
    PH(0, 0, 0, 1, STG_A(15, 0), WV4);
    PH(0, 1, 0, 0, STG_B(15, 0), WV4);
    PH(0, 0, 1, 1, STG_A(15, 1), WV4);
    PH(0, 1, 1, 0, STG_B(15, 1), WV4);
    PH(1, 0, 0, 1, NOS, WV2);
    PH(1, 1, 0, 0, NOS, WV0);
    PH(1, 0, 1, 1, NOS, NOV);
    PH(1, 1, 1, 0, NOS, NOV);

    // fused epilogue: masked pos/neg max per output row
    // C/D layout: col = lane&15 (proto), row = (lane>>4)*4 + reg (batch)
    const int col00 = colbase + wn * 64 + lm;
    #pragma unroll
    for (int mi = 0; mi < 8; ++mi) {
        #pragma unroll
        for (int r = 0; r < 4; ++r) {
            const int row_g = rowbase + wm * 128 + mi * 16 + lk * 4 + r;
            const int yv = y[row_g];
            float pm = -INFINITY, nm = -INFINITY;
            #pragma unroll
            for (int ni = 0; ni < 4; ++ni) {
                const int col_g = col00 + ni * 16;
                const float v = acc[mi][ni][r];
                const bool same = (col_g / 5) == yv;
                if (same) pm = fmaxf(pm, v);
                else if (col_g < NPROTO) nm = fmaxf(nm, v);
            }
            #pragma unroll
            for (int off = 1; off < 16; off <<= 1) {
                pm = fmaxf(pm, __shfl_xor(pm, off));
                nm = fmaxf(nm, __shfl_xor(nm, off));
            }
            if (lm == 0) {
                if (pm > -INFINITY) atomicMax(&posU[row_g], enc_f32(pm));
                if (nm > -INFINITY) atomicMax(&negU[row_g], enc_f32(nm));
            }
        }
    }
#undef PH
#undef STG_A
#undef STG_B
}

// ---------- decode to output ----------
__global__ __launch_bounds__(256) void k_finish(
        const unsigned* __restrict__ posU, const unsigned* __restrict__ negU,
        float* __restrict__ out) {
    const int i = blockIdx.x * 256 + threadIdx.x;
    if (i < BATCH) {
        out[i] = dec_f32(posU[i]);
        out[BATCH + i] = dec_f32(negU[i]);
    }
}

extern "C" void kernel_launch(void* const* d_in, const int* in_sizes, int n_in,
                              void* d_out, int out_size, void* d_ws, size_t ws_size,
                              hipStream_t stream) {
    const float* z = (const float*)d_in[0];
    const int*   y = (const int*)d_in[1];
    const float* P = (const float*)d_in[2];

    unsigned short* zb = (unsigned short*)d_ws;
    unsigned short* pb = zb + (size_t)BATCH * D;
    unsigned* posU = (unsigned*)(pb + (size_t)NPROTO_PAD * D);
    unsigned* negU = posU + BATCH;
    float* out = (float*)d_out;

    k_prep<<<BATCH + NPROTO_PAD, 256, 0, stream>>>(z, P, zb, pb, posU, negU);
    k_gemm<<<NBLK, 512, 0, stream>>>(zb, pb, y, posU, negU);
    k_finish<<<BATCH / 256, 256, 0, stream>>>(posU, negU, out);
}

// Round 6
// 277.539 us; speedup vs baseline: 1.0618x; 1.0424x over previous
//
#include <hip/hip_runtime.h>
#include <hip/hip_bf16.h>
#include <stdint.h>

#define BATCH 16384
#define D 1024
#define NCLS 1000
#define NPROTO 5000
#define NPROTO_PAD 5120
#define BM 256
#define BN 256
#define BK 64
#define NKT (D / BK)         // 16 K-tiles
#define NIT (NKT / 2)        // 8 iterations, 2 K-tiles each
#define NBLK ((NPROTO_PAD / BN) * (BATCH / BM))   // 20 * 64 = 1280

typedef float f32x4 __attribute__((ext_vector_type(4)));
typedef __bf16 bf16x8 __attribute__((ext_vector_type(8)));

__device__ __forceinline__ unsigned short f2bf(float x) {
    unsigned u = __float_as_uint(x);
    u += 0x7FFFu + ((u >> 16) & 1u);   // RNE
    return (unsigned short)(u >> 16);
}
__device__ __forceinline__ unsigned enc_f32(float f) {
    unsigned u = __float_as_uint(f);
    return (u & 0x80000000u) ? ~u : (u | 0x80000000u);
}
__device__ __forceinline__ float dec_f32(unsigned e) {
    return __uint_as_float((e & 0x80000000u) ? (e ^ 0x80000000u) : ~e);
}

// ---------- normalize rows of z and P to bf16 (K-tiled layouts) ----------
// zbt[kt][BATCH][64]    : A staging, K-tile-major, rows contiguous
// pbh[kt][ks][NPAD][32] : B staging, K-half-major, rows contiguous
__global__ __launch_bounds__(256) void k_prep(
        const float* __restrict__ z, const float* __restrict__ P,
        unsigned short* __restrict__ zbt, unsigned short* __restrict__ pbh,
        unsigned* __restrict__ posU, unsigned* __restrict__ negU) {
    const int b = blockIdx.x;
    const int t = threadIdx.x;
    if (b < BATCH && t == 0) {
        posU[b] = enc_f32(-INFINITY);
        negU[b] = enc_f32(-INFINITY);
    }
    const int e0 = 4 * t;
    const int kt = e0 >> 6;
    const float* src = nullptr;
    unsigned short* dst;
    if (b < BATCH) {
        src = z + (size_t)b * D;
        dst = zbt + ((size_t)kt * BATCH + b) * 64 + (e0 & 63);
    } else {
        const int r = b - BATCH;
        const int ks = (e0 >> 5) & 1;
        dst = pbh + (((size_t)kt * 2 + ks) * NPROTO_PAD + r) * 32 + (e0 & 31);
        if (r < NPROTO) src = P + (size_t)r * D;
    }
    if (src == nullptr) {                 // padded proto row -> zeros
        *(ushort4*)dst = make_ushort4(0, 0, 0, 0);
        return;
    }
    float4 v = ((const float4*)src)[t];
    float ss = v.x * v.x + v.y * v.y + v.z * v.z + v.w * v.w;
    #pragma unroll
    for (int off = 32; off >= 1; off >>= 1) ss += __shfl_xor(ss, off);
    __shared__ float red[4];
    const int wave = t >> 6;
    if ((t & 63) == 0) red[wave] = ss;
    __syncthreads();
    const float s = red[0] + red[1] + red[2] + red[3];
    const float inv = 1.0f / fmaxf(sqrtf(s), 1e-12f);
    ushort4 o;
    o.x = f2bf(v.x * inv); o.y = f2bf(v.y * inv);
    o.z = f2bf(v.z * inv); o.w = f2bf(v.w * inv);
    *(ushort4*)dst = o;
}

// async global->LDS, 16B per lane, dest = wave-uniform base + lane*16
#define GLL(gp, lp) __builtin_amdgcn_global_load_lds( \
    (__attribute__((address_space(1))) const unsigned int*)(const void*)(gp), \
    (__attribute__((address_space(3))) unsigned int*)(void*)(lp), 16, 0, 0)

#define MM(A, B, C) __builtin_amdgcn_mfma_f32_16x16x32_bf16(A, B, C, 0, 0, 0)

// ---------- 256x256 bf16 GEMM, 8-phase, coalesced staging + XOR swizzle ----
// LDS: LA[buf][256][64] row-major (128B rows); LB[buf][ks][256][32].
// Swizzle involution: byte ^= ((byte>>7)&7)<<4, applied to GLL SOURCE and
// ds_read address (linear GLL dest) -> every GLL reads contiguous 1KB;
// fragment reads are 2-way bank-aliased (free).
__global__ __launch_bounds__(512, 2) void k_gemm(
        const unsigned short* __restrict__ zbt,
        const unsigned short* __restrict__ pbh,
        const int* __restrict__ y,
        unsigned* __restrict__ posU, unsigned* __restrict__ negU) {
    __shared__ __align__(16) unsigned short LA[2][256][64];      // 64 KiB
    __shared__ __align__(16) unsigned short LB[2][2][256][32];   // 64 KiB

    const int t = threadIdx.x;
    const int w = t >> 6;
    const int lane = t & 63;
    const int lm = lane & 15, lk = lane >> 4;
    const int wm = w >> 2, wn = w & 3;       // 2(M) x 4(N) wave grid

    // XCD-aware decode (T1): bid&7 = xcd, 8-block runs share a B col-panel
    const int bid = blockIdx.x;
    const int yy = (bid & 7) * 8 + ((bid >> 3) & 7);   // row-tile 0..63
    const int cc = bid >> 6;                           // col-tile 0..19
    const int rowbase = yy * BM;
    const int colbase = cc * BN;

    // per-lane swizzled staging source offsets (elems), j = 0,1
    const int o0 = w * 2048 + lane * 16;
    const int o1 = o0 + 1024;
    const int offsw0 = (o0 ^ (((o0 >> 7) & 7) << 4)) >> 1;
    const int offsw1 = (o1 ^ (((o1 >> 7) & 7) << 4)) >> 1;

    // per-lane ds_read swizzle constants
    const int kslA0 = ((0 * 4 + lk) ^ (lm & 7)) << 4;             // bytes
    const int kslA1 = ((1 * 4 + lk) ^ (lm & 7)) << 4;
    const int slB   = ((((lm & 1) * 4 + lk) ^ ((lm >> 1) & 7))) << 4;

#define STG_A(T, H) do {                                                     \
    const size_t sA_ = (size_t)(T) * (BATCH * 64) +                          \
                       (size_t)(rowbase + (H) * 128) * 64;                   \
    unsigned short* dA_ = (unsigned short*)&LA[(T) & 1][(H) * 128][0];       \
    GLL(zbt + sA_ + offsw0, dA_ + w * 1024);                                 \
    GLL(zbt + sA_ + offsw1, dA_ + w * 1024 + 512);                           \
} while (0)
#define STG_B(T, KS) do {                                                    \
    const size_t sB_ = ((size_t)((T) * 2 + (KS)) * NPROTO_PAD + colbase)*32; \
    unsigned short* dB_ = (unsigned short*)&LB[(T) & 1][KS][0][0];           \
    GLL(pbh + sB_ + offsw0, dB_ + w * 1024);                                 \
    GLL(pbh + sB_ + offsw1, dB_ + w * 1024 + 512);                           \
} while (0)

// A frag (sub S of 4, half MH, k-half KS): row = MH*128 + wm*64 + S*16 + lm
#define LDA(CBUF, MH, S, KS)                                                 \
    (*(const bf16x8*)((const unsigned short*)&LA[CBUF][0][0] +               \
        ((((MH) * 128 + wm * 64 + (S) * 16 + lm) * 128 +                     \
          ((KS) ? kslA1 : kslA0)) >> 1)))
// B frag (sub NI of 4, k-half KS): row = wn*64 + NI*16 + lm
#define LDB(CBUF, NI, KS)                                                    \
    (*(const bf16x8*)((const unsigned short*)&LB[CBUF][KS][0][0] +           \
        (((wn * 32 + (NI) * 8 + (lm >> 1)) * 128 + slB) >> 1)))

#define WV4 asm volatile("s_waitcnt vmcnt(4)" ::: "memory")
#define WV2 asm volatile("s_waitcnt vmcnt(2)" ::: "memory")
#define WV0 asm volatile("s_waitcnt vmcnt(0)" ::: "memory")
#define NOV ((void)0)
#define NOS ((void)0)

    f32x4 acc[8][4];
    #pragma unroll
    for (int i = 0; i < 8; ++i)
        #pragma unroll
        for (int j = 0; j < 4; ++j) {
            f32x4 z4 = {0.0f, 0.0f, 0.0f, 0.0f};
            acc[i][j] = z4;
        }

    bf16x8 b0_, b1_, b2_, b3_;

// phase: reads -> stage -> barrier -> lgkm0 -> 16 MFMA -> vmcnt -> barrier
#define PH(CBUF, MH, KS, RB, STG, WAIT) do {                             \
    const bf16x8 a0_ = LDA(CBUF, MH, 0, KS);                             \
    const bf16x8 a1_ = LDA(CBUF, MH, 1, KS);                             \
    const bf16x8 a2_ = LDA(CBUF, MH, 2, KS);                             \
    const bf16x8 a3_ = LDA(CBUF, MH, 3, KS);                             \
    if (RB) {                                                            \
        b0_ = LDB(CBUF, 0, KS);                                          \
        b1_ = LDB(CBUF, 1, KS);                                          \
        b2_ = LDB(CBUF, 2, KS);                                          \
        b3_ = LDB(CBUF, 3, KS);                                          \
    }                                                                    \
    STG;                                                                 \
    asm volatile("s_barrier" ::: "memory");                              \
    asm volatile("s_waitcnt lgkmcnt(0)" ::: "memory");                   \
    __builtin_amdgcn_s_setprio(1);                                       \
    acc[4 * (MH) + 0][0] = MM(a0_, b0_, acc[4 * (MH) + 0][0]);           \
    acc[4 * (MH) + 0][1] = MM(a0_, b1_, acc[4 * (MH) + 0][1]);           \
    acc[4 * (MH) + 0][2] = MM(a0_, b2_, acc[4 * (MH) + 0][2]);           \
    acc[4 * (MH) + 0][3] = MM(a0_, b3_, acc[4 * (MH) + 0][3]);           \
    acc[4 * (MH) + 1][0] = MM(a1_, b0_, acc[4 * (MH) + 1][0]);           \
    acc[4 * (MH) + 1][1] = MM(a1_, b1_, acc[4 * (MH) + 1][1]);           \
    acc[4 * (MH) + 1][2] = MM(a1_, b2_, acc[4 * (MH) + 1][2]);           \
    acc[4 * (MH) + 1][3] = MM(a1_, b3_, acc[4 * (MH) + 1][3]);           \
    acc[4 * (MH) + 2][0] = MM(a2_, b0_, acc[4 * (MH) + 2][0]);           \
    acc[4 * (MH) + 2][1] = MM(a2_, b1_, acc[4 * (MH) + 2][1]);           \
    acc[4 * (MH) + 2][2] = MM(a2_, b2_, acc[4 * (MH) + 2][2]);           \
    acc[4 * (MH) + 2][3] = MM(a2_, b3_, acc[4 * (MH) + 2][3]);           \
    acc[4 * (MH) + 3][0] = MM(a3_, b0_, acc[4 * (MH) + 3][0]);           \
    acc[4 * (MH) + 3][1] = MM(a3_, b1_, acc[4 * (MH) + 3][1]);           \
    acc[4 * (MH) + 3][2] = MM(a3_, b2_, acc[4 * (MH) + 3][2]);           \
    acc[4 * (MH) + 3][3] = MM(a3_, b3_, acc[4 * (MH) + 3][3]);           \
    __builtin_amdgcn_s_setprio(0);                                       \
    WAIT;                                                                \
    asm volatile("s_barrier" ::: "memory");                              \
} while (0)

    // prologue: stage tile 0 (A-H0, B-K0, A-H1, B-K1), drain, barrier
    STG_A(0, 0); STG_B(0, 0); STG_A(0, 1); STG_B(0, 1);
    WV0;
    asm volatile("s_barrier" ::: "memory");

    // iter i: compute tile 2i (buf0, P1-4) + tile 2i+1 (buf1, P5-8).
    // stage units (1/phase): P1 A(o1,H0) P2 B(o1,K0) P3 A(o1,H1) P4 B(o1,K1)
    //                        P5 A(e2,H0) P6 B(e2,K0) P7 A(e2,H1) P8 B(e2,K1)
    // all consume lags >= 3 phases; vmcnt(4) at each phase end completes
    // everything staged >= 2 phases ago -> race-free.
    #pragma unroll 1
    for (int i = 0; i < NIT - 1; ++i) {
        const int o1 = 2 * i + 1, e2 = 2 * i + 2;
        PH(0, 0, 0, 1, STG_A(o1, 0), WV4);
        PH(0, 1, 0, 0, STG_B(o1, 0), WV4);
        PH(0, 0, 1, 1, STG_A(o1, 1), WV4);
        PH(0, 1, 1, 0, STG_B(o1, 1), WV4);
        PH(1, 0, 0, 1, STG_A(e2, 0), WV4);
        PH(1, 1, 0, 0, STG_B(e2, 0), WV4);
        PH(1, 0, 1, 1, STG_A(e2, 1), WV4);
        PH(1, 1, 1, 0, STG_B(e2, 1), WV4);
    }
    // tail iter: tiles 14,15; stage only tile 15; waits 4,4,4,4,2,0,-,-
    PH(0, 0, 0, 1, STG_A(15, 0), WV4);
    PH(0, 1, 0, 0, STG_B(15, 0), WV4);
    PH(0, 0, 1, 1, STG_A(15, 1), WV4);
    PH(0, 1, 1, 0, STG_B(15, 1), WV4);
    PH(1, 0, 0, 1, NOS, WV2);
    PH(1, 1, 0, 0, NOS, WV0);
    PH(1, 0, 1, 1, NOS, NOV);
    PH(1, 1, 1, 0, NOS, NOV);

    // fused epilogue: masked pos/neg max per output row
    // C/D layout: col = lane&15 (proto), row = (lane>>4)*4 + reg (batch)
    // acc mi -> global row: rowbase + (mi>>2)*128 + wm*64 + (mi&3)*16
    const int col00 = colbase + wn * 64 + lm;
    #pragma unroll
    for (int mi = 0; mi < 8; ++mi) {
        #pragma unroll
        for (int r = 0; r < 4; ++r) {
            const int row_g = rowbase + (mi >> 2) * 128 + wm * 64 +
                              (mi & 3) * 16 + lk * 4 + r;
            const int yv = y[row_g];
            float pm = -INFINITY, nm = -INFINITY;
            #pragma unroll
            for (int ni = 0; ni < 4; ++ni) {
                const int col_g = col00 + ni * 16;
                const float v = acc[mi][ni][r];
                const bool same = (col_g / 5) == yv;
                if (same) pm = fmaxf(pm, v);
                else if (col_g < NPROTO) nm = fmaxf(nm, v);
            }
            #pragma unroll
            for (int off = 1; off < 16; off <<= 1) {
                pm = fmaxf(pm, __shfl_xor(pm, off));
                nm = fmaxf(nm, __shfl_xor(nm, off));
            }
            if (lm == 0) {
                if (pm > -INFINITY) atomicMax(&posU[row_g], enc_f32(pm));
                if (nm > -INFINITY) atomicMax(&negU[row_g], enc_f32(nm));
            }
        }
    }
#undef PH
#undef STG_A
#undef STG_B
#undef LDA
#undef LDB
}

// ---------- decode to output ----------
__global__ __launch_bounds__(256) void k_finish(
        const unsigned* __restrict__ posU, const unsigned* __restrict__ negU,
        float* __restrict__ out) {
    const int i = blockIdx.x * 256 + threadIdx.x;
    if (i < BATCH) {
        out[i] = dec_f32(posU[i]);
        out[BATCH + i] = dec_f32(negU[i]);
    }
}

extern "C" void kernel_launch(void* const* d_in, const int* in_sizes, int n_in,
                              void* d_out, int out_size, void* d_ws, size_t ws_size,
                              hipStream_t stream) {
    const float* z = (const float*)d_in[0];
    const int*   y = (const int*)d_in[1];
    const float* P = (const float*)d_in[2];

    // ws: zbt 33.5MB | pbh 10.5MB | posU 64KB | negU 64KB
    unsigned short* zbt = (unsigned short*)d_ws;
    unsigned short* pbh = zbt + (size_t)NKT * BATCH * 64;
    unsigned* posU = (unsigned*)(pbh + (size_t)NKT * 2 * NPROTO_PAD * 32);
    unsigned* negU = posU + BATCH;
    float* out = (float*)d_out;

    k_prep<<<BATCH + NPROTO_PAD, 256, 0, stream>>>(z, P, zbt, pbh, posU, negU);
    k_gemm<<<NBLK, 512, 0, stream>>>(zbt, pbh, y, posU, negU);
    k_finish<<<BATCH / 256, 256, 0, stream>>>(posU, negU, out);
}